// Round 4
// baseline (2725.521 us; speedup 1.0000x reference)
//
#include <hip/hip_runtime.h>
#include <cfloat>

// Problem constants
#define NROWS   32768      // 8*4096 z vectors
#define NCODES  8192
#define KDIM    256
#define QOUT_OFFSET (NROWS * KDIM)

// Tiling
#define BM 64
#define BN 128
#define BK 32
#define THREADS 256
#define NITER (NCODES / BN * KDIM / BK)   // 64 ct * 8 kc = 512

// ---------------------------------------------------------------------------
// Kernel 1: cnorm[m] = ||codebook[m]||^2.  One wave per code row.
// ---------------------------------------------------------------------------
__global__ void vq_cnorm_kernel(const float* __restrict__ cb,
                                float* __restrict__ cnorm) {
    int gid  = blockIdx.x * blockDim.x + threadIdx.x;
    int code = gid >> 6;
    int lane = threadIdx.x & 63;
    if (code >= NCODES) return;
    float4 v = ((const float4*)cb)[code * (KDIM / 4) + lane];
    float s = v.x * v.x + v.y * v.y + v.z * v.z + v.w * v.w;
    #pragma unroll
    for (int off = 32; off >= 1; off >>= 1)
        s += __shfl_down(s, off, 64);
    if (lane == 0) cnorm[code] = s;
}

// ---------------------------------------------------------------------------
// Kernel 2: fused distance GEMM + argmin + gather.
// 256 threads (4 waves). Block owns BM=64 rows, scans all 8192 codes.
// LDS tiles row-major [row][k], XOR-swizzled at float4 granularity:
//   chunk kk (0..7) of row r stored at float4-slot r*8 + (kk ^ (r&7)).
// Staging = plain float4 copy (conflict-free). Compute = float4-dot
// micro-kernel. Register-prefetch double buffer hides global latency.
// ---------------------------------------------------------------------------
__global__ __launch_bounds__(THREADS) void vq_main_kernel(
        const float* __restrict__ z, const float* __restrict__ cb,
        const float* __restrict__ cnorm, float* __restrict__ quant,
        float* __restrict__ idx_out) {

    __shared__ float4 As4[BM * 8];    // 64 rows * 8 chunks = 8 KB
    __shared__ float4 Bs4[BN * 8];    // 128 rows * 8 chunks = 16 KB
    __shared__ int    bestIdx[BM];

    const int t    = threadIdx.x;
    const int tj   = t & 31;         // codes tj + 32c, c=0..3
    const int tr   = t >> 5;         // rows tr*8 + r, r=0..7
    const int row0 = blockIdx.x * BM;

    // staging mapping: lane t loads chunk kk=t&7 of row t>>3 (+32i)
    const int srow = t >> 3;         // 0..31
    const int skk  = t & 7;
    const int sxor = skk ^ (srow & 7);   // same for srow+32* (row&7 invariant)

    const float4* z4  = (const float4*)z;
    const float4* cb4 = (const float4*)cb;

    float acc[8][4];
    float minv[8];
    int   mini[8];
    #pragma unroll
    for (int r = 0; r < 8; ++r) {
        minv[r] = FLT_MAX; mini[r] = 0;
        #pragma unroll
        for (int c = 0; c < 4; ++c) acc[r][c] = 0.f;
    }

    // ---- prologue: fetch tile 0 into registers ----
    float4 pa[2], pb[4];
    {
        #pragma unroll
        for (int i = 0; i < 2; ++i)
            pa[i] = z4[(size_t)(row0 + srow + 32 * i) * (KDIM / 4) + skk];
        #pragma unroll
        for (int i = 0; i < 4; ++i)
            pb[i] = cb4[(size_t)(srow + 32 * i) * (KDIM / 4) + skk];
    }

    for (int iter = 0; iter < NITER; ++iter) {
        const int ct = iter >> 3;
        const int kc = iter & 7;

        __syncthreads();   // prev compute done; LDS free
        // ---- store prefetched regs to LDS (swizzled, conflict-free) ----
        #pragma unroll
        for (int i = 0; i < 2; ++i)
            As4[(srow + 32 * i) * 8 + sxor] = pa[i];
        #pragma unroll
        for (int i = 0; i < 4; ++i)
            Bs4[(srow + 32 * i) * 8 + sxor] = pb[i];
        __syncthreads();

        // ---- issue next tile's global loads (latency hidden by compute) ----
        if (iter + 1 < NITER) {
            const int nct = (iter + 1) >> 3;
            const int nkc = (iter + 1) & 7;
            #pragma unroll
            for (int i = 0; i < 2; ++i)
                pa[i] = z4[(size_t)(row0 + srow + 32 * i) * (KDIM / 4) + nkc * 8 + skk];
            #pragma unroll
            for (int i = 0; i < 4; ++i)
                pb[i] = cb4[(size_t)(nct * BN + srow + 32 * i) * (KDIM / 4) + nkc * 8 + skk];
        }

        // ---- compute: 8 chunks of 4-deep dot, 8 rows x 4 codes ----
        #pragma unroll
        for (int kk = 0; kk < 8; ++kk) {
            float4 a[8], b[4];
            #pragma unroll
            for (int r = 0; r < 8; ++r)
                a[r] = As4[(tr * 8 + r) * 8 + (kk ^ r)];         // (tr*8+r)&7 == r
            #pragma unroll
            for (int c = 0; c < 4; ++c)
                b[c] = Bs4[(tj + 32 * c) * 8 + (kk ^ (tj & 7))]; // (tj+32c)&7 == tj&7
            #pragma unroll
            for (int r = 0; r < 8; ++r)
                #pragma unroll
                for (int c = 0; c < 4; ++c) {
                    acc[r][c] = fmaf(a[r].x, b[c].x, acc[r][c]);
                    acc[r][c] = fmaf(a[r].y, b[c].y, acc[r][c]);
                    acc[r][c] = fmaf(a[r].z, b[c].z, acc[r][c]);
                    acc[r][c] = fmaf(a[r].w, b[c].w, acc[r][c]);
                }
        }

        // ---- per-code-tile epilogue: dist = ||c||^2 - 2 z.c, running argmin
        if (kc == 7) {
            #pragma unroll
            for (int c = 0; c < 4; ++c) {
                int code = ct * BN + 32 * c + tj;    // ascending in (ct, c)
                float cn = cnorm[code];
                #pragma unroll
                for (int r = 0; r < 8; ++r) {
                    float d = fmaf(-2.f, acc[r][c], cn);
                    if (d < minv[r]) { minv[r] = d; mini[r] = code; }
                    acc[r][c] = 0.f;
                }
            }
        }
    }

    // ---- cross-thread argmin: 32-lane shuffle tree per row ----
    #pragma unroll
    for (int r = 0; r < 8; ++r) {
        float v  = minv[r];
        int   id = mini[r];
        #pragma unroll
        for (int off = 16; off >= 1; off >>= 1) {
            float ov  = __shfl_down(v, off, 64);
            int   oid = __shfl_down(id, off, 64);
            if (ov < v || (ov == v && oid < id)) { v = ov; id = oid; }
        }
        if (tj == 0) {
            bestIdx[tr * 8 + r] = id;
            idx_out[row0 + tr * 8 + r] = (float)id;
        }
    }
    __syncthreads();

    // ---- gather codebook rows into quantized output (bit-exact fp32) ----
    {
        int row = t >> 2, seg = t & 3;
        int best = bestIdx[row];
        const float4* src = &cb4[(size_t)best * (KDIM / 4)];
        float4* dst = (float4*)quant + (size_t)(row0 + row) * (KDIM / 4);
        #pragma unroll
        for (int i = 0; i < 16; ++i)
            dst[seg * 16 + i] = src[seg * 16 + i];
    }
}

// ---------------------------------------------------------------------------
extern "C" void kernel_launch(void* const* d_in, const int* in_sizes, int n_in,
                              void* d_out, int out_size, void* d_ws, size_t ws_size,
                              hipStream_t stream) {
    const float* z  = (const float*)d_in[0];
    const float* cb = (const float*)d_in[1];
    float* quant   = (float*)d_out;
    float* idx_out = (float*)d_out + QOUT_OFFSET;
    float* cnorm   = (float*)d_ws;            // 8192 floats

    vq_cnorm_kernel<<<NCODES / 4, 256, 0, stream>>>(cb, cnorm);
    vq_main_kernel<<<NROWS / BM, THREADS, 0, stream>>>(z, cb, cnorm, quant, idx_out);
}

// Round 5
// 560.629 us; speedup vs baseline: 4.8615x; 4.8615x over previous
//
#include <hip/hip_runtime.h>
#include <cfloat>
#include <stdint.h>

// Problem constants
#define NROWS   32768
#define NCODES  8192
#define KDIM    256
#define QOUT_OFFSET (NROWS * KDIM)

// Main-kernel tiling
#define BM      128            // rows per block
#define BN      256            // codes per code-tile
#define BK      32             // k per chunk
#define NCT     (NCODES / BN)  // 32
#define NKC     (KDIM / BK)    // 8
#define NIT     (NCT * NKC)    // 256 iterations
#define THREADS 512            // 8 waves

// Panel geometry (bf16, 32 k per row + 16B pad -> conflict-free frag reads)
#define ROWB 80
#define APAN (BM * ROWB)       // 10240 B per split
#define BPAN (BN * ROWB)       // 20480 B per split
#define ABUF (2 * APAN)        // hi+lo 20480 B
#define BBUF (2 * BPAN)        // hi+lo 40960 B

typedef __bf16 bf16x4 __attribute__((ext_vector_type(4)));
typedef __bf16 bf16x8 __attribute__((ext_vector_type(8)));
typedef float  f32x4  __attribute__((ext_vector_type(4)));

// ---------------------------------------------------------------------------
// K0: cnorm[m] = ||codebook[m]||^2 (exact fp32). One wave per code row.
// ---------------------------------------------------------------------------
__global__ void vq_cnorm_kernel(const float* __restrict__ cb,
                                float* __restrict__ cnorm) {
    int gid  = blockIdx.x * blockDim.x + threadIdx.x;
    int code = gid >> 6;
    int lane = threadIdx.x & 63;
    if (code >= NCODES) return;
    float4 v = ((const float4*)cb)[code * (KDIM / 4) + lane];
    float s = v.x * v.x + v.y * v.y + v.z * v.z + v.w * v.w;
    #pragma unroll
    for (int off = 32; off >= 1; off >>= 1)
        s += __shfl_down(s, off, 64);
    if (lane == 0) cnorm[code] = s;
}

// ---------------------------------------------------------------------------
// K1: build codebook hi/lo bf16 panels in scratch (quant region of d_out).
// Panel (ct,kc): [256 codes x 80 B] hi, then [256 x 80 B] lo  = 40960 B.
// Block = 256 thr handles 64 codes; thread: row=t>>2, seg=t&3 (16 float4).
// ---------------------------------------------------------------------------
__global__ void vq_panel_kernel(const float* __restrict__ cb,
                                char* __restrict__ cbP) {
    const int t   = threadIdx.x;
    const int c0  = blockIdx.x * 64;
    const int row = t >> 2;
    const int seg = t & 3;
    const int code = c0 + row;
    const int ct  = code >> 8;        // /256
    const int cl  = code & 255;
    const float4* cb4 = (const float4*)cb;

    #pragma unroll
    for (int i = 0; i < 16; ++i) {
        int f = seg * 16 + i;                 // float4 index in row, 0..63
        float4 v = cb4[(size_t)code * 64 + f];
        int k  = f * 4;
        int kc = k >> 5;
        int kl = k & 31;
        bf16x4 h, l;
        float xs[4] = {v.x, v.y, v.z, v.w};
        #pragma unroll
        for (int e = 0; e < 4; ++e) {
            __bf16 hh = (__bf16)xs[e];
            h[e] = hh;
            l[e] = (__bf16)(xs[e] - (float)hh);
        }
        char* base = cbP + ((size_t)(ct * NKC + kc)) * BBUF
                         + (size_t)cl * ROWB + (size_t)kl * 2;
        *(bf16x4*)base          = h;
        *(bf16x4*)(base + BPAN) = l;
    }
}

// ---------------------------------------------------------------------------
// async 16B global->LDS copy (wave-uniform LDS base + lane*16)
// ---------------------------------------------------------------------------
__device__ __forceinline__ void async_copy16(const void* g, void* l) {
    __builtin_amdgcn_global_load_lds(
        (const __attribute__((address_space(1))) uint32_t*)g,
        (__attribute__((address_space(3))) uint32_t*)l, 16, 0, 0);
}

// ---------------------------------------------------------------------------
// K2: distances via split-bf16 MFMA + argmin. Writes idx floats only.
// 8 waves: mw = w&1 (two 64-row stripes), nw = w>>1 (four 64-code stripes).
// Wave tile 64x64 = 4x4 MFMA 16x16 tiles; 3 split products per tile.
// ---------------------------------------------------------------------------
__global__ __launch_bounds__(THREADS, 2) void vq_main_kernel(
        const float* __restrict__ z, const char* __restrict__ cbP,
        const float* __restrict__ cnorm, float* __restrict__ idx_out) {

    __shared__ __align__(16) char ldsbuf[2 * ABUF + 2 * BBUF];  // 122880 B
    __shared__ float cnS[NCODES];                               // 32768 B

    const int t    = threadIdx.x;
    const int wave = t >> 6;
    const int lane = t & 63;
    const int mw   = wave & 1;
    const int nw   = wave >> 1;
    const int row0 = blockIdx.x * BM;
    const int l15  = lane & 15;
    const int q16  = (lane >> 4) * 16;     // byte offset of k-octet in row

    const float4* z4 = (const float4*)z;

    // staging ids for A (z): thread t -> row t>>2, k-segment t&3
    const int arow = t >> 2;
    const int aseg = t & 3;

    // preload full cnorm into LDS
    #pragma unroll
    for (int i = 0; i < NCODES / THREADS; ++i)
        cnS[t + THREADS * i] = cnorm[t + THREADS * i];

    f32x4 acc[4][4];
    float mv[16];
    int   mi[16];
    #pragma unroll
    for (int i = 0; i < 4; ++i)
        #pragma unroll
        for (int j = 0; j < 4; ++j)
            acc[i][j] = (f32x4){0.f, 0.f, 0.f, 0.f};
    #pragma unroll
    for (int s = 0; s < 16; ++s) { mv[s] = FLT_MAX; mi[s] = 0; }

    // ---- prologue: stage iteration 0 into buffer 0 ----
    {
        // B async: 40 chunks of 1024 B, 5 per wave
        char* Bdst = ldsbuf + 2 * ABUF;
        #pragma unroll
        for (int c = 0; c < 5; ++c) {
            int off = (wave * 5 + c) * 1024 + lane * 16;
            async_copy16(cbP + off, Bdst + off);
        }
        // A: load z (kc=0), convert, write
        float4 za = z4[(size_t)(row0 + arow) * 64 + aseg * 2 + 0];
        float4 zb = z4[(size_t)(row0 + arow) * 64 + aseg * 2 + 1];
        float xs[8] = {za.x, za.y, za.z, za.w, zb.x, zb.y, zb.z, zb.w};
        bf16x8 hv, lv;
        #pragma unroll
        for (int e = 0; e < 8; ++e) {
            __bf16 hh = (__bf16)xs[e];
            hv[e] = hh;
            lv[e] = (__bf16)(xs[e] - (float)hh);
        }
        char* Adst = ldsbuf;
        *(bf16x8*)(Adst + arow * ROWB + aseg * 16)        = hv;
        *(bf16x8*)(Adst + APAN + arow * ROWB + aseg * 16) = lv;
    }

    for (int n = 0; n < NIT; ++n) {
        const int ct = n >> 3;
        const int kc = n & 7;
        const int p  = n & 1;

        __syncthreads();   // buffers[p] ready (vmcnt+lgkm drained), buffers[p^1] free

        const char* Ab = ldsbuf + p * ABUF;
        const char* Bb = ldsbuf + 2 * ABUF + p * BBUF;

        // ---- issue async B staging for n+1 into buffer p^1 ----
        if (n + 1 < NIT) {
            const char* gsrc = cbP + (size_t)(n + 1) * BBUF;
            char* Bdst = ldsbuf + 2 * ABUF + (p ^ 1) * BBUF;
            #pragma unroll
            for (int c = 0; c < 5; ++c) {
                int off = (wave * 5 + c) * 1024 + lane * 16;
                async_copy16(gsrc + off, Bdst + off);
            }
        }
        // ---- issue z loads for n+1 (consumed after compute) ----
        float4 za, zb;
        if (n + 1 < NIT) {
            int kc1 = (n + 1) & 7;
            za = z4[(size_t)(row0 + arow) * 64 + kc1 * 8 + aseg * 2 + 0];
            zb = z4[(size_t)(row0 + arow) * 64 + kc1 * 8 + aseg * 2 + 1];
        }

        // ---- compute: 3-phase split products, 16 tiles each ----
        bf16x8 ah[4], bh[4], bl[4], al[4];
        #pragma unroll
        for (int i = 0; i < 4; ++i)
            ah[i] = *(const bf16x8*)(Ab + (mw * 64 + i * 16 + l15) * ROWB + q16);
        #pragma unroll
        for (int j = 0; j < 4; ++j)
            bh[j] = *(const bf16x8*)(Bb + (nw * 64 + j * 16 + l15) * ROWB + q16);
        #pragma unroll
        for (int i = 0; i < 4; ++i)
            #pragma unroll
            for (int j = 0; j < 4; ++j)
                acc[i][j] = __builtin_amdgcn_mfma_f32_16x16x32_bf16(
                                ah[i], bh[j], acc[i][j], 0, 0, 0);
        #pragma unroll
        for (int j = 0; j < 4; ++j)
            bl[j] = *(const bf16x8*)(Bb + BPAN + (nw * 64 + j * 16 + l15) * ROWB + q16);
        #pragma unroll
        for (int i = 0; i < 4; ++i)
            #pragma unroll
            for (int j = 0; j < 4; ++j)
                acc[i][j] = __builtin_amdgcn_mfma_f32_16x16x32_bf16(
                                ah[i], bl[j], acc[i][j], 0, 0, 0);
        #pragma unroll
        for (int i = 0; i < 4; ++i)
            al[i] = *(const bf16x8*)(Ab + APAN + (mw * 64 + i * 16 + l15) * ROWB + q16);
        #pragma unroll
        for (int i = 0; i < 4; ++i)
            #pragma unroll
            for (int j = 0; j < 4; ++j)
                acc[i][j] = __builtin_amdgcn_mfma_f32_16x16x32_bf16(
                                al[i], bh[j], acc[i][j], 0, 0, 0);

        // ---- epilogue at end of code-tile: dist = ||c||^2 - 2 z.c ----
        if (kc == 7) {
            #pragma unroll
            for (int j = 0; j < 4; ++j) {
                int code = ct * BN + nw * 64 + j * 16 + l15;
                float cn = cnS[code];
                #pragma unroll
                for (int i = 0; i < 4; ++i) {
                    #pragma unroll
                    for (int r = 0; r < 4; ++r) {
                        float d = fmaf(-2.f, acc[i][j][r], cn);
                        int s = i * 4 + r;
                        if (d < mv[s]) { mv[s] = d; mi[s] = code; }
                    }
                    acc[i][j] = (f32x4){0.f, 0.f, 0.f, 0.f};
                }
            }
        }

        // ---- convert + LDS-write A for n+1 into buffer p^1 ----
        if (n + 1 < NIT) {
            float xs[8] = {za.x, za.y, za.z, za.w, zb.x, zb.y, zb.z, zb.w};
            bf16x8 hv, lv;
            #pragma unroll
            for (int e = 0; e < 8; ++e) {
                __bf16 hh = (__bf16)xs[e];
                hv[e] = hh;
                lv[e] = (__bf16)(xs[e] - (float)hh);
            }
            char* Adst = ldsbuf + (p ^ 1) * ABUF;
            *(bf16x8*)(Adst + arow * ROWB + aseg * 16)        = hv;
            *(bf16x8*)(Adst + APAN + arow * ROWB + aseg * 16) = lv;
        }
    }

    // ---- reduction: 16-lane butterfly per (i,reg), then cross-wave via LDS
    #pragma unroll
    for (int s = 0; s < 16; ++s) {
        #pragma unroll
        for (int m = 1; m <= 8; m <<= 1) {
            float ov = __shfl_xor(mv[s], m, 64);
            int   oi = __shfl_xor(mi[s], m, 64);
            if (ov < mv[s] || (ov == mv[s] && oi < mi[s])) { mv[s] = ov; mi[s] = oi; }
        }
    }
    __syncthreads();   // safe to reuse ldsbuf
    float* redV = (float*)ldsbuf;              // [4 nw][128 rows]
    int*   redI = (int*)(ldsbuf + 4 * BM * 4); // [4 nw][128 rows]
    if (l15 == 0) {
        int q = lane >> 4;
        #pragma unroll
        for (int i = 0; i < 4; ++i)
            #pragma unroll
            for (int r = 0; r < 4; ++r) {
                int ml = mw * 64 + i * 16 + q * 4 + r;
                redV[nw * BM + ml] = mv[i * 4 + r];
                redI[nw * BM + ml] = mi[i * 4 + r];
            }
    }
    __syncthreads();
    if (t < BM) {
        float bv = redV[t];
        int   bi = redI[t];
        #pragma unroll
        for (int w = 1; w < 4; ++w) {
            float v  = redV[w * BM + t];
            int   id = redI[w * BM + t];
            if (v < bv || (v == bv && id < bi)) { bv = v; bi = id; }
        }
        idx_out[row0 + t] = (float)bi;
    }
}

// ---------------------------------------------------------------------------
// K3: gather codebook rows into quantized output (bit-exact fp32).
// Separate dispatch => global barrier; overwrites the cbP scratch region.
// ---------------------------------------------------------------------------
__global__ void vq_gather_kernel(const float* __restrict__ cb,
                                 const float* __restrict__ idx_f,
                                 float* __restrict__ quant) {
    const int t   = threadIdx.x;
    const int row = blockIdx.x * 64 + (t >> 2);
    const int seg = t & 3;
    const int best = (int)idx_f[row];
    const float4* src = (const float4*)cb + (size_t)best * (KDIM / 4);
    float4* dst = (float4*)quant + (size_t)row * (KDIM / 4);
    #pragma unroll
    for (int i = 0; i < 16; ++i)
        dst[seg * 16 + i] = src[seg * 16 + i];
}

// ---------------------------------------------------------------------------
extern "C" void kernel_launch(void* const* d_in, const int* in_sizes, int n_in,
                              void* d_out, int out_size, void* d_ws, size_t ws_size,
                              hipStream_t stream) {
    const float* z  = (const float*)d_in[0];
    const float* cb = (const float*)d_in[1];
    float* quant   = (float*)d_out;
    float* idx_out = (float*)d_out + QOUT_OFFSET;
    float* cnorm   = (float*)d_ws;           // 32 KB scratch
    char*  cbP     = (char*)d_out;           // 10.5 MB panel scratch inside
                                             // quant region; K3 overwrites it

    vq_cnorm_kernel<<<NCODES / 4, 256, 0, stream>>>(cb, cnorm);
    vq_panel_kernel<<<NCODES / 64, 256, 0, stream>>>(cb, cbP);
    vq_main_kernel<<<NROWS / BM, THREADS, 0, stream>>>(z, cbP, cnorm, idx_out);
    vq_gather_kernel<<<NROWS / 64, 256, 0, stream>>>(cb, idx_out, quant);
}